// Round 11
// baseline (715.581 us; speedup 1.0000x reference)
//
#include <hip/hip_runtime.h>

typedef __bf16 bfx8 __attribute__((ext_vector_type(8)));
typedef float f32x4 __attribute__((ext_vector_type(4)));
typedef unsigned short u16x8 __attribute__((ext_vector_type(8)));

#define MFMA16(a, b, c) __builtin_amdgcn_mfma_f32_16x16x32_bf16((a), (b), (c), 0, 0, 0)

#define GLOAD16(gp, lp)                                                        \
  __builtin_amdgcn_global_load_lds(                                            \
      (const __attribute__((address_space(1))) unsigned int*)(gp),             \
      (__attribute__((address_space(3))) unsigned int*)(lp), 16, 0, 0)

#define FENCE() __builtin_amdgcn_sched_barrier(0)  // compile-time fence: caps
                                                   // cross-phase hoisting (R10
                                                   // spill antidote), 0 cycles

// Geometry: x (8, 256, 16384) fp32; mem (200, 256) fp32; out (8, 256, 16384) fp32.
// Slots padded 200 -> 256 with zero rows.

// ---------------- prep: mem -> bf16 hi/lo + permuted-transposed hi ----------------
// MTp[c][kidx] = hi(mem[sigma(kidx)][c]), sigma(32ks+8h+4t+r) -> slot 32ks+16t+4h+r,
// so the PV B-operand is a pure in-register repack of the score accumulators.
__global__ __launch_bounds__(256) void prep_mem(const float* __restrict__ mem,
                                                unsigned short* __restrict__ Mh,
                                                unsigned short* __restrict__ Ml,
                                                unsigned short* __restrict__ MTp) {
  const int s = blockIdx.x;   // slot (padded)
  const int c = threadIdx.x;  // channel
  const float v = (s < 200) ? mem[s * 256 + c] : 0.0f;
  const __bf16 hi = (__bf16)v;
  const __bf16 lo = (__bf16)(v - (float)hi);
  const unsigned short hib = __builtin_bit_cast(unsigned short, hi);
  const unsigned short lob = __builtin_bit_cast(unsigned short, lo);
  Mh[s * 256 + c] = hib;
  Ml[s * 256 + c] = lob;
  const int ks = s >> 5, w = s & 31;
  const int t = w >> 4, hh = (w >> 2) & 3, rr = w & 3;
  MTp[c * 256 + (ks * 32 + hh * 8 + t * 4 + rr)] = hib;
}

// ---------------- fused kernel ----------------
// Block = 16 waves x 16 tokens = 256 tokens/tile, 1024 threads.
// Grid = 256, PERSISTENT over 2 tiles (gtok = (bid + tile*256)*256).
// LDS 128KB = ALL 8 Mh slices, staged ONCE, read-only for both tiles.
// Ml (score lo-part) and MTp (PV A-operand) fragments come DIRECT from L2/L1.
// Output stored direct from registers (R7-proven exact WRITE_SIZE).
// => exactly ONE runtime barrier in the kernel; waves skew freely, so tile0's
// non-blocking stores drain under tile1's reads (read/write pipe overlap).
__global__ __launch_bounds__(1024, 4) void fused_mem_attn(
    const float* __restrict__ x, const unsigned short* __restrict__ Mh,
    const unsigned short* __restrict__ Ml, const unsigned short* __restrict__ MTp,
    float* __restrict__ out) {
  __shared__ alignas(128) char lds[131072];

  const int tid = threadIdx.x;   // 0..1023
  const int wave = tid >> 6;     // 0..15
  const int lane = tid & 63;
  const int t16 = lane & 15;
  const int h = lane >> 4;

  // mem staging swizzle (proven pair): thread owns physical 16B-block tid of
  // each 16KB slice; fetches logical Lb = tid ^ ((tid>>3)&7) (involution).
  const int Lb = tid ^ ((tid >> 3) & 7);
  const int srcOff = (Lb >> 2) * 512 + (Lb & 3) * 16;  // byte in [256 rows][64B]
  // Reader-side swizzled 16B-block offset within a 1KB (16-row) tile.
  const int q16 = ((((t16 << 2) + h) ^ (t16 >> 1)) << 4);

  const char* MhB = (const char*)Mh;
  const char* MlB = (const char*)Ml;
  const char* MTB = (const char*)MTp;

  // ---- prologue: stage all 8 Mh slices; the kernel's ONLY barrier ----
#pragma unroll
  for (int ks = 0; ks < 8; ++ks)
    GLOAD16(MhB + srcOff + ks * 64, lds + ks * 16384 + tid * 16);
  __syncthreads();

#define XLOAD(ks)                                                              \
  _Pragma("unroll") for (int j = 0; j < 8; ++j) {                              \
    xr[(ks) % 3][j] = xb[(long)((ks) * 32 + h * 8 + j) << 14];                 \
  }

#define COMPUTE(ks)                                                            \
  {                                                                            \
    if ((ks) < 6) XLOAD((ks) + 2);                                             \
    bfx8 xh, xl;                                                               \
    _Pragma("unroll") for (int j = 0; j < 8; ++j) {                            \
      const float f = xr[(ks) % 3][j];                                         \
      const __bf16 hi_ = (__bf16)f;                                            \
      xh[j] = hi_;                                                             \
      xl[j] = (__bf16)(f - (float)hi_);                                        \
    }                                                                          \
    const char* sb = lds + (ks) * 16384;                                       \
    __builtin_amdgcn_s_setprio(1);                                             \
    _Pragma("unroll") for (int tt = 0; tt < 13; ++tt) {                        \
      const bfx8 ah = *(const bfx8*)(sb + tt * 1024 + q16);                    \
      const u16x8 mlu =                                                        \
          *(const u16x8*)(MlB + (tt * 16 + t16) * 512 + (ks) * 64 + h * 16);   \
      const bfx8 al = __builtin_bit_cast(bfx8, mlu);                           \
      acc[tt] = MFMA16(ah, xh, acc[tt]);                                       \
      acc[tt] = MFMA16(al, xh, acc[tt]);                                       \
      acc[tt] = MFMA16(ah, xl, acc[tt]);                                       \
    }                                                                          \
    __builtin_amdgcn_s_setprio(0);                                             \
    FENCE();                                                                   \
  }

  for (int tile = 0; tile < 2; ++tile) {
    const long gtok0 = ((long)blockIdx.x + (long)tile * 256) * 256;
    const int b = (int)(gtok0 >> 14);
    const int bn0 = (int)(gtok0 & 16383);
    const float* xb = x + ((long)b << 22) + bn0 + (wave * 16 + t16);
    float* outB = out + ((long)b << 22) + bn0 + (wave * 16 + t16);

    float xr[3][8];
    f32x4 acc[14] = {};  // acc[13] stays exactly 0 (padding slots 208..223)

    // ---- score phase: barrier-free, per-slice compile-time fences ----
    XLOAD(0);
    XLOAD(1);
    COMPUTE(0) COMPUTE(1) COMPUTE(2) COMPUTE(3)
    COMPUTE(4) COMPUTE(5) COMPUTE(6) COMPUTE(7)

    // ---- softmax over slots (token column = lane&15; slot row = 4h+r) ----
    float m = -3.0e38f;
#pragma unroll
    for (int tt = 0; tt < 12; ++tt)
#pragma unroll
      for (int r = 0; r < 4; ++r) m = fmaxf(m, acc[tt][r]);
#pragma unroll
    for (int r = 0; r < 4; ++r)
      if (192 + h * 4 + r < 200) m = fmaxf(m, acc[12][r]);
    m = fmaxf(m, __shfl_xor(m, 16, 64));
    m = fmaxf(m, __shfl_xor(m, 32, 64));
    float s = 0.f;
#pragma unroll
    for (int tt = 0; tt < 12; ++tt)
#pragma unroll
      for (int r = 0; r < 4; ++r) {
        const float p = __expf(acc[tt][r] - m);
        acc[tt][r] = p;
        s += p;
      }
#pragma unroll
    for (int r = 0; r < 4; ++r) {
      const bool ok = (192 + h * 4 + r) < 200;
      const float p = ok ? __expf(acc[12][r] - m) : 0.f;
      acc[12][r] = p;
      s += p;
    }
    s += __shfl_xor(s, 16, 64);
    s += __shfl_xor(s, 32, 64);
    const float inv = 1.f / s;

    // ---- repack P into PV B-fragments in registers (sigma baked into MTp) ----
    bfx8 pb[7];
#pragma unroll
    for (int k = 0; k < 7; ++k)
#pragma unroll
      for (int j = 0; j < 4; ++j) {
        pb[k][j] = (__bf16)acc[2 * k][j];
        pb[k][j + 4] = (__bf16)acc[2 * k + 1][j];
      }
    FENCE();

    // ---- PV + fused epilogue: one channel-tile at a time, A direct from L2;
    //      stores issue immediately (non-blocking) and drain under the next
    //      tile's reads. Fence every 2 cts caps load-hoisting (spill guard). ----
#pragma unroll
    for (int ct = 0; ct < 16; ++ct) {
      f32x4 a2 = {0.f, 0.f, 0.f, 0.f};
#pragma unroll
      for (int k = 0; k < 7; ++k) {
        const u16x8 atu =
            *(const u16x8*)(MTB + (ct * 16 + t16) * 512 + k * 64 + h * 16);
        const bfx8 at = __builtin_bit_cast(bfx8, atu);
        a2 = MFMA16(at, pb[k], a2);
      }
#pragma unroll
      for (int r = 0; r < 4; ++r)
        outB[(long)(ct * 16 + h * 4 + r) << 14] = a2[r] * inv;
      if (ct & 1) FENCE();
    }
  }
#undef XLOAD
#undef COMPUTE
}

extern "C" void kernel_launch(void* const* d_in, const int* in_sizes, int n_in,
                              void* d_out, int out_size, void* d_ws, size_t ws_size,
                              hipStream_t stream) {
  const float* x = (const float*)d_in[0];
  const float* mem = (const float*)d_in[1];
  float* out = (float*)d_out;

  unsigned short* Mh = (unsigned short*)d_ws;  // [256][256] bf16 hi
  unsigned short* Ml = Mh + 256 * 256;         // [256][256] bf16 lo
  unsigned short* MTp = Ml + 256 * 256;        // [256][256] bf16 hi, [c][kidx] permuted

  prep_mem<<<dim3(256), dim3(256), 0, stream>>>(mem, Mh, Ml, MTp);
  fused_mem_attn<<<dim3(256), dim3(1024), 0, stream>>>(x, Mh, Ml, MTp, out);
}

// Round 12
// 70.316 us; speedup vs baseline: 10.1766x; 10.1766x over previous
//
#include <hip/hip_runtime.h>

typedef _Float16 h16x8 __attribute__((ext_vector_type(8)));
typedef float f32x4 __attribute__((ext_vector_type(4)));

#define MFMA16F(a, b, c) __builtin_amdgcn_mfma_f32_16x16x32_f16((a), (b), (c), 0, 0, 0)

#define GLOAD16(gp, lp)                                                        \
  __builtin_amdgcn_global_load_lds(                                            \
      (const __attribute__((address_space(1))) unsigned int*)(gp),             \
      (__attribute__((address_space(3))) unsigned int*)(lp), 16, 0, 0)

#define FENCE() __builtin_amdgcn_sched_barrier(0)

// Geometry: x (8, 256, 16384) fp32; mem (200, 256) fp32; out (8, 256, 16384) fp32.
// Slots padded 200 -> 256 with zero rows.
//
// Numerics: score = fp16 2-pass split (m16·xh + m16·xl, fp32 accum); logit err
// ~3e-3. PV = fp16 P × fp16 mem (p rel err 2^-12, better than prior bf16 2^-9).

// ---------------- prep: mem -> fp16 (row-major) + fp16 permuted-transposed ----------------
// MT16[c][kidx] = fp16(mem[sigma(kidx)][c]), sigma(32ks+8h+4t+r) -> slot 32ks+16t+4h+r,
// so the PV B-operand is a pure in-register repack of the score accumulators.
__global__ __launch_bounds__(256) void prep_mem(const float* __restrict__ mem,
                                                unsigned short* __restrict__ M16,
                                                unsigned short* __restrict__ MT16) {
  const int s = blockIdx.x;   // slot (padded)
  const int c = threadIdx.x;  // channel
  const float v = (s < 200) ? mem[s * 256 + c] : 0.0f;
  const _Float16 hv = (_Float16)v;
  const unsigned short hb = __builtin_bit_cast(unsigned short, hv);
  M16[s * 256 + c] = hb;
  const int ks = s >> 5, w = s & 31;
  const int t = w >> 4, hh = (w >> 2) & 3, rr = w & 3;
  MT16[c * 256 + (ks * 32 + hh * 8 + t * 4 + rr)] = hb;
}

// ---------------- fused kernel ----------------
// Block = 16 waves x 16 tokens = 256 tokens, 1024 threads. Grid = 512.
// LDS 128KB = ALL 8 M16 slices resident -> score phase is BARRIER-FREE and
// has ZERO global fragment loads (the R10/R11 spill source is gone): only the
// bounded 2-deep x prefetch is in flight (per-wave compiler-counted vmcnt).
// 3 runtime barriers total: post-Mh-stage, post-score, post-MT16-stage.
__global__ __launch_bounds__(1024, 4) void fused_mem_attn(
    const float* __restrict__ x, const unsigned short* __restrict__ M16,
    const unsigned short* __restrict__ MT16, float* __restrict__ out) {
  __shared__ alignas(128) char lds[131072];

  const int tid = threadIdx.x;   // 0..1023
  const int wave = tid >> 6;     // 0..15
  const int lane = tid & 63;
  const int t16 = lane & 15;
  const int h = lane >> 4;

  // mem staging swizzle (proven pair): thread owns physical 16B-block tid of
  // each 16KB slice; fetches logical Lb = tid ^ ((tid>>3)&7) (involution).
  const int Lb = tid ^ ((tid >> 3) & 7);
  const int srcOff = (Lb >> 2) * 512 + (Lb & 3) * 16;  // byte in [256 rows][64B]
  // Reader-side swizzled 16B-block offset within a 1KB (16-row) tile.
  const int q16 = ((((t16 << 2) + h) ^ (t16 >> 1)) << 4);

  const long gtok0 = (long)blockIdx.x * 256;
  const int b = (int)(gtok0 >> 14);
  const int bn0 = (int)(gtok0 & 16383);
  const float* xb = x + ((long)b << 22) + bn0 + (wave * 16 + t16);
  float* outB = out + ((long)b << 22) + bn0 + (wave * 16 + t16);

  const char* M16B = (const char*)M16;
  const char* MTB = (const char*)MT16;

#define XLOAD(ks)                                                              \
  _Pragma("unroll") for (int j = 0; j < 8; ++j) {                              \
    xr[(ks) % 3][j] = xb[(long)((ks) * 32 + h * 8 + j) << 14];                 \
  }

  float xr[3][8];
  f32x4 acc[14] = {};  // acc[13] stays exactly 0 (padding slots 208..223)

#define COMPUTE(ks)                                                            \
  {                                                                            \
    if ((ks) < 6) XLOAD((ks) + 2);                                             \
    h16x8 xh, xl;                                                              \
    _Pragma("unroll") for (int j = 0; j < 8; ++j) {                            \
      const float f = xr[(ks) % 3][j];                                         \
      const _Float16 hi_ = (_Float16)f;                                        \
      xh[j] = hi_;                                                             \
      xl[j] = (_Float16)(f - (float)hi_);                                      \
    }                                                                          \
    const char* sb = lds + (ks) * 16384;                                       \
    __builtin_amdgcn_s_setprio(1);                                             \
    _Pragma("unroll") for (int tt = 0; tt < 13; ++tt) {                        \
      const h16x8 ah = *(const h16x8*)(sb + tt * 1024 + q16);                  \
      acc[tt] = MFMA16F(ah, xh, acc[tt]);                                      \
      acc[tt] = MFMA16F(ah, xl, acc[tt]);                                      \
    }                                                                          \
    __builtin_amdgcn_s_setprio(0);                                             \
    FENCE();                                                                   \
  }

  // ---- prologue: 2-deep x prefetch + stage ALL 8 M16 slices; barrier #1 ----
  XLOAD(0);
  XLOAD(1);
#pragma unroll
  for (int ks = 0; ks < 8; ++ks)
    GLOAD16(M16B + srcOff + ks * 64, lds + ks * 16384 + tid * 16);
  __syncthreads();

  // ---- score phase: BARRIER-FREE, zero global fragment loads ----
  COMPUTE(0) COMPUTE(1) COMPUTE(2) COMPUTE(3)
  COMPUTE(4) COMPUTE(5) COMPUTE(6) COMPUTE(7)

  __syncthreads();  // barrier #2: all waves done reading M16 LDS

  // ---- stage ALL of MT16 (7 x 16KB) over the dead score slices;
  //      fill latency hides under the register-only softmax + repack ----
#pragma unroll
  for (int k = 0; k < 7; ++k)
    GLOAD16(MTB + srcOff + k * 64, lds + k * 16384 + tid * 16);

  // ---- softmax over slots (token column = lane&15; slot row = 4h+r) ----
  float m = -3.0e38f;
#pragma unroll
  for (int tt = 0; tt < 12; ++tt)
#pragma unroll
    for (int r = 0; r < 4; ++r) m = fmaxf(m, acc[tt][r]);
#pragma unroll
  for (int r = 0; r < 4; ++r)
    if (192 + h * 4 + r < 200) m = fmaxf(m, acc[12][r]);
  m = fmaxf(m, __shfl_xor(m, 16, 64));
  m = fmaxf(m, __shfl_xor(m, 32, 64));
  float s = 0.f;
#pragma unroll
  for (int tt = 0; tt < 12; ++tt)
#pragma unroll
    for (int r = 0; r < 4; ++r) {
      const float p = __expf(acc[tt][r] - m);
      acc[tt][r] = p;
      s += p;
    }
#pragma unroll
  for (int r = 0; r < 4; ++r) {
    const bool ok = (192 + h * 4 + r) < 200;
    const float p = ok ? __expf(acc[12][r] - m) : 0.f;
    acc[12][r] = p;
    s += p;
  }
  s += __shfl_xor(s, 16, 64);
  s += __shfl_xor(s, 32, 64);
  const float inv = 1.f / s;

  // ---- repack P into PV B-fragments in registers (sigma baked into MT16) ----
  h16x8 pb[7];
#pragma unroll
  for (int k = 0; k < 7; ++k)
#pragma unroll
    for (int j = 0; j < 4; ++j) {
      pb[k][j] = (_Float16)acc[2 * k][j];
      pb[k][j + 4] = (_Float16)acc[2 * k + 1][j];
    }

  __syncthreads();  // barrier #3: MT16 resident

  // ---- PV + fused epilogue: barrier-free, LDS A-fragments, per-ct stores
  //      issue immediately so the write stream drains under later PV work ----
#pragma unroll
  for (int ct = 0; ct < 16; ++ct) {
    f32x4 a2 = {0.f, 0.f, 0.f, 0.f};
    __builtin_amdgcn_s_setprio(1);
#pragma unroll
    for (int k = 0; k < 7; ++k) {
      const h16x8 at = *(const h16x8*)(lds + k * 16384 + ct * 1024 + q16);
      a2 = MFMA16F(at, pb[k], a2);
    }
    __builtin_amdgcn_s_setprio(0);
#pragma unroll
    for (int r = 0; r < 4; ++r)
      outB[(long)(ct * 16 + h * 4 + r) << 14] = a2[r] * inv;
  }
#undef XLOAD
#undef COMPUTE
}

extern "C" void kernel_launch(void* const* d_in, const int* in_sizes, int n_in,
                              void* d_out, int out_size, void* d_ws, size_t ws_size,
                              hipStream_t stream) {
  const float* x = (const float*)d_in[0];
  const float* mem = (const float*)d_in[1];
  float* out = (float*)d_out;

  unsigned short* M16 = (unsigned short*)d_ws;   // [256][256] fp16
  unsigned short* MT16 = M16 + 256 * 256;        // [256][256] fp16, [c][kidx] permuted

  prep_mem<<<dim3(256), dim3(256), 0, stream>>>(mem, M16, MT16);
  fused_mem_attn<<<dim3(512), dim3(1024), 0, stream>>>(x, M16, MT16, out);
}

// Round 13
// 68.664 us; speedup vs baseline: 10.4214x; 1.0241x over previous
//
#include <hip/hip_runtime.h>

typedef _Float16 h16x8 __attribute__((ext_vector_type(8)));
typedef float f32x4 __attribute__((ext_vector_type(4)));

#define MFMA16F(a, b, c) __builtin_amdgcn_mfma_f32_16x16x32_f16((a), (b), (c), 0, 0, 0)

#define GLOAD16(gp, lp)                                                        \
  __builtin_amdgcn_global_load_lds(                                            \
      (const __attribute__((address_space(1))) unsigned int*)(gp),             \
      (__attribute__((address_space(3))) unsigned int*)(lp), 16, 0, 0)

#define FENCE() __builtin_amdgcn_sched_barrier(0)

// Geometry: x (8, 256, 16384) fp32; mem (200, 256) fp32; out (8, 256, 16384) fp32.
// Slots padded 200 -> 256 with zero rows.
//
// Score: fp16 2-pass split (m16*xh + m16*xl, fp32 accum) -- R12-proven.
// PV: reoriented as D[tok][c] = P*M so the A-operand is a PURE-REGISTER view of
// the score accumulators: with k-order s(32kk+8h+j) = 32kk+16(j>>2)+4h+(j&3),
// pa[kk][j] = inv*acc[2kk+(j>>2)][j&3] (same lane, no shuffle). B = mem in a
// B-fragment-linear pre-tiled table MB (conflict-free linear LDS reads, no
// swizzle), and the output C-layout gives 16B dwordx4 token-contiguous stores.

// ---------------- prep: mem -> fp16 M16 (row-major) + MB (B-frag-tiled) ----------------
__global__ __launch_bounds__(256) void prep_mem(const float* __restrict__ mem,
                                                unsigned short* __restrict__ M16,
                                                unsigned short* __restrict__ MB) {
  const int s = blockIdx.x;   // slot (padded 0..255)
  const int c = threadIdx.x;  // channel
  const float v = (s < 200) ? mem[s * 256 + c] : 0.0f;
  const _Float16 hv = (_Float16)v;
  const unsigned short hb = __builtin_bit_cast(unsigned short, hv);
  M16[s * 256 + c] = hb;
  if (s < 224) {
    // invert s(kk,h,j): s = 32kk + 16*(j>>2) + 4h + (j&3)
    const int kk = s >> 5;
    const int th = (s >> 4) & 1;   // j>>2
    const int hh = (s >> 2) & 3;
    const int rr = s & 3;          // j&3
    const int j = th * 4 + rr;
    // element idx = kk*8192 + (c>>4)*512 + hh*128 + (c&15)*8 + j
    MB[kk * 8192 + (c >> 4) * 512 + hh * 128 + (c & 15) * 8 + j] = hb;
  }
}

// ---------------- fused kernel ----------------
// Block = 16 waves x 16 tokens = 256 tokens, 1024 threads. Grid = 512.
// LDS 128KB = ALL 8 M16 slices resident; score phase BARRIER-FREE (only the
// bounded 2-deep x prefetch in flight). 3 runtime barriers total. MB (7x16KB)
// staged over dead M16 slices, fill hidden under softmax/repack.
__global__ __launch_bounds__(1024, 4) void fused_mem_attn(
    const float* __restrict__ x, const unsigned short* __restrict__ M16,
    const unsigned short* __restrict__ MB, float* __restrict__ out) {
  __shared__ alignas(128) char lds[131072];

  const int tid = threadIdx.x;   // 0..1023
  const int wave = tid >> 6;     // 0..15
  const int lane = tid & 63;
  const int t16 = lane & 15;
  const int h = lane >> 4;

  // Score-table staging swizzle (proven pair): thread owns physical 16B-block
  // tid of each 16KB slice; fetches logical Lb = tid ^ ((tid>>3)&7).
  const int Lb = tid ^ ((tid >> 3) & 7);
  const int srcOff = (Lb >> 2) * 512 + (Lb & 3) * 16;  // byte in [256 rows][64B]
  // Reader-side swizzled 16B-block offset within a 1KB (16-row) tile.
  const int q16 = ((((t16 << 2) + h) ^ (t16 >> 1)) << 4);

  const long gtok0 = (long)blockIdx.x * 256;
  const int b = (int)(gtok0 >> 14);
  const int bn0 = (int)(gtok0 & 16383);
  const float* xb = x + ((long)b << 22) + bn0 + (wave * 16 + t16);
  // PV store base: token = wave*16 + 4h + r (r in the f32x4), channel = ct*16+t16
  float* outT = out + ((long)b << 22) + bn0 + (wave * 16 + 4 * h) + ((long)t16 << 14);

  const char* M16B = (const char*)M16;
  const char* MBB = (const char*)MB;

#define XLOAD(ks)                                                              \
  _Pragma("unroll") for (int j = 0; j < 8; ++j) {                              \
    xr[(ks) % 3][j] = xb[(long)((ks) * 32 + h * 8 + j) << 14];                 \
  }

  float xr[3][8];
  f32x4 acc[14] = {};  // acc[13] stays exactly 0 (padding slots 208..223)

#define COMPUTE(ks)                                                            \
  {                                                                            \
    if ((ks) < 6) XLOAD((ks) + 2);                                             \
    h16x8 xh, xl;                                                              \
    _Pragma("unroll") for (int j = 0; j < 8; ++j) {                            \
      const float f = xr[(ks) % 3][j];                                         \
      const _Float16 hi_ = (_Float16)f;                                        \
      xh[j] = hi_;                                                             \
      xl[j] = (_Float16)(f - (float)hi_);                                      \
    }                                                                          \
    const char* sb = lds + (ks) * 16384;                                       \
    __builtin_amdgcn_s_setprio(1);                                             \
    _Pragma("unroll") for (int tt = 0; tt < 13; ++tt) {                        \
      const h16x8 ah = *(const h16x8*)(sb + tt * 1024 + q16);                  \
      acc[tt] = MFMA16F(ah, xh, acc[tt]);                                      \
      acc[tt] = MFMA16F(ah, xl, acc[tt]);                                      \
    }                                                                          \
    __builtin_amdgcn_s_setprio(0);                                             \
    FENCE();                                                                   \
  }

  // ---- prologue: 2-deep x prefetch + stage ALL 8 M16 slices; barrier #1 ----
  XLOAD(0);
  XLOAD(1);
#pragma unroll
  for (int ks = 0; ks < 8; ++ks)
    GLOAD16(M16B + srcOff + ks * 64, lds + ks * 16384 + tid * 16);
  __syncthreads();

  // ---- score phase: BARRIER-FREE, zero global fragment loads ----
  COMPUTE(0) COMPUTE(1) COMPUTE(2) COMPUTE(3)
  COMPUTE(4) COMPUTE(5) COMPUTE(6) COMPUTE(7)

  __syncthreads();  // barrier #2: all waves done reading M16 LDS

  // ---- stage ALL of MB (7 x 16KB, LINEAR dest/src: no swizzle needed) over
  //      the dead score slices; fill hides under softmax + repack ----
#pragma unroll
  for (int k = 0; k < 7; ++k)
    GLOAD16(MBB + k * 16384 + tid * 16, lds + k * 16384 + tid * 16);

  // ---- softmax over slots (token column = lane&15; slot row = 4h+r) ----
  float m = -3.0e38f;
#pragma unroll
  for (int tt = 0; tt < 12; ++tt)
#pragma unroll
    for (int r = 0; r < 4; ++r) m = fmaxf(m, acc[tt][r]);
#pragma unroll
  for (int r = 0; r < 4; ++r)
    if (192 + h * 4 + r < 200) m = fmaxf(m, acc[12][r]);
  m = fmaxf(m, __shfl_xor(m, 16, 64));
  m = fmaxf(m, __shfl_xor(m, 32, 64));
  float s = 0.f;
#pragma unroll
  for (int tt = 0; tt < 12; ++tt)
#pragma unroll
    for (int r = 0; r < 4; ++r) {
      const float p = __expf(acc[tt][r] - m);
      acc[tt][r] = p;
      s += p;
    }
#pragma unroll
  for (int r = 0; r < 4; ++r) {
    const bool ok = (192 + h * 4 + r) < 200;
    const float p = ok ? __expf(acc[12][r] - m) : 0.f;
    acc[12][r] = p;
    s += p;
  }
  s += __shfl_xor(s, 16, 64);
  s += __shfl_xor(s, 32, 64);
  const float inv = 1.f / s;

  // ---- repack P into PV A-fragments, inv folded in (pure register):
  //      pa[kk][j] = inv * acc[2kk + (j>>2)][j&3]  (same lane, same h) ----
  h16x8 pa[7];
#pragma unroll
  for (int kk = 0; kk < 7; ++kk)
#pragma unroll
    for (int j = 0; j < 8; ++j)
      pa[kk][j] = (_Float16)(inv * acc[2 * kk + (j >> 2)][j & 3]);

  __syncthreads();  // barrier #3: MB resident

  // ---- PV: D[tok][c] = P*M. B-fragments linear from LDS (conflict-free);
  //      output f32x4 = 4 consecutive tokens -> ONE 16B dwordx4 store ----
#pragma unroll
  for (int ct = 0; ct < 16; ++ct) {
    f32x4 a2 = {0.f, 0.f, 0.f, 0.f};
    __builtin_amdgcn_s_setprio(1);
#pragma unroll
    for (int kk = 0; kk < 7; ++kk) {
      const h16x8 bt = *(const h16x8*)(lds + kk * 16384 + ct * 1024 + lane * 16);
      a2 = MFMA16F(pa[kk], bt, a2);
    }
    __builtin_amdgcn_s_setprio(0);
    *(f32x4*)(outT + ((long)ct << 18)) = a2;
  }
#undef XLOAD
#undef COMPUTE
}

extern "C" void kernel_launch(void* const* d_in, const int* in_sizes, int n_in,
                              void* d_out, int out_size, void* d_ws, size_t ws_size,
                              hipStream_t stream) {
  const float* x = (const float*)d_in[0];
  const float* mem = (const float*)d_in[1];
  float* out = (float*)d_out;

  unsigned short* M16 = (unsigned short*)d_ws;   // [256][256] fp16 row-major
  unsigned short* MB = M16 + 256 * 256;          // [7][16][4][16][8] fp16 B-frag tiling

  prep_mem<<<dim3(256), dim3(256), 0, stream>>>(mem, M16, MB);
  fused_mem_attn<<<dim3(512), dim3(1024), 0, stream>>>(x, M16, MB, out);
}